// Round 9
// baseline (660.909 us; speedup 1.0000x reference)
//
#include <hip/hip_runtime.h>

#define NB 8
#define NP 1024
#define NR 8192

typedef unsigned short u16;
typedef __attribute__((ext_vector_type(8))) short bf16x8;   // 8 bf16 (4 VGPRs)
typedef __attribute__((ext_vector_type(4))) float f32x4;

#define MFMA __builtin_amdgcn_mfma_f32_16x16x32_bf16

static __device__ __forceinline__ float bf2f(u16 u) {
    union { unsigned int i; float f; } v; v.i = ((unsigned int)u) << 16; return v.f;
}
static __device__ __forceinline__ unsigned int f2bf(float f) {
    union { float fv; unsigned int i; } v; v.fv = f;
    unsigned int r = v.i + 0x7FFFu + ((v.i >> 16) & 1u);   // RNE
    return r >> 16;
}
static __device__ __forceinline__ unsigned int pack2(float a, float b) {
    return f2bf(a) | (f2bf(b) << 16);
}
static __device__ __forceinline__ void unpk8(uint4 v, float* o) {
    o[0] = bf2f((u16)(v.x & 0xFFFF)); o[1] = bf2f((u16)(v.x >> 16));
    o[2] = bf2f((u16)(v.y & 0xFFFF)); o[3] = bf2f((u16)(v.y >> 16));
    o[4] = bf2f((u16)(v.z & 0xFFFF)); o[5] = bf2f((u16)(v.z >> 16));
    o[6] = bf2f((u16)(v.w & 0xFFFF)); o[7] = bf2f((u16)(v.w >> 16));
}

// ------- fused: blocks 0..7 = weight prep; blocks 8.. = one-hot index scan -------
// Scan: 4 chunks per thread per matrix (8 independent dwordx4 loads in flight)
// to cover HBM latency — round-8 profile showed 2-loads/thread ran at 19% peak.
__global__ __launch_bounds__(256) void k_idxprep(
    const uint4* __restrict__ Rr4, const uint4* __restrict__ Rs4,
    u16* __restrict__ recv, u16* __restrict__ send,
    const float* __restrict__ w0, const float* __restrict__ w1,
    const float* __restrict__ w2, const float* __restrict__ w3,
    const float* __restrict__ w4, const float* __restrict__ w5,
    const float* __restrict__ w6, const float* __restrict__ w7,
    bf16x8* __restrict__ wfrag)
{
    int tid = threadIdx.x;
    if (blockIdx.x < 8) {                     // ---- weight prep path ----
        const float* W; int KC, kv, off;
        switch (blockIdx.x) {
            case 0:  W = w0; KC = 3;  kv = 65;  off = 0;  break;   // re_w0 (pad 65->96)
            case 1:  W = w1; KC = 4;  kv = 128; off = 6;  break;   // re_w1
            case 2:  W = w2; KC = 4;  kv = 128; off = 14; break;   // re_w2
            case 3:  W = w3; KC = 1;  kv = 32;  off = 22; break;   // pe_w0
            case 4:  W = w4; KC = 4;  kv = 128; off = 24; break;   // pe_w1
            case 5:  W = w5; KC = 12; kv = 384; off = 32; break;   // rp_w
            case 6:  W = w6; KC = 8;  kv = 256; off = 56; break;   // pp_w
            default: W = w7; KC = 4;  kv = 128; off = 72; break;   // pr_w0
        }
        int wave = tid >> 6, quad = (tid >> 4) & 3, l16 = tid & 15;
        for (int kc = 0; kc < KC; ++kc)
          for (int nt = 0; nt < 2; ++nt) {
            bf16x8 f;
            #pragma unroll
            for (int j = 0; j < 8; ++j) {
                int k = kc*32 + quad*8 + j;
                f[j] = (k < kv) ? (short)f2bf(W[k*128 + wave*32 + nt*16 + l16]) : (short)0;
            }
            wfrag[(off + kc*2 + nt)*256 + tid] = f;
          }
        return;
    }
    // ---- index scan path: block covers 1024 consecutive 16B chunks ----
    long blk0 = (long)(blockIdx.x - 8) * 1024;
    uint4 vr[4], vs[4];
    #pragma unroll
    for (int u = 0; u < 4; ++u) {
        long i = blk0 + u * 256 + tid;
        vr[u] = Rr4[i];
        vs[u] = Rs4[i];
    }
    #pragma unroll
    for (int u = 0; u < 4; ++u) {
        long i = blk0 + u * 256 + tid;
        int c4 = (int)(i & 2047);          // chunk within r-row (R/4 = 2048)
        int n  = (int)((i >> 11) & 1023);
        int b  = (int)(i >> 21);
        int base = b * NR + c4 * 4;
        if (vr[u].x) recv[base + 0] = (u16)n;
        if (vr[u].y) recv[base + 1] = (u16)n;
        if (vr[u].z) recv[base + 2] = (u16)n;
        if (vr[u].w) recv[base + 3] = (u16)n;
        if (vs[u].x) send[base + 0] = (u16)n;
        if (vs[u].y) send[base + 1] = (u16)n;
        if (vs[u].z) send[base + 2] = (u16)n;
        if (vs[u].w) send[base + 3] = (u16)n;
    }
}

// ------- CSR: LDS histogram + scan; emits row_ptr, inverse perm pos[], send_sorted[] -------
__global__ __launch_bounds__(1024) void k_csr(
    const u16* __restrict__ recv, const u16* __restrict__ send,
    int* __restrict__ row_ptr, u16* __restrict__ pos,
    u16* __restrict__ send_sorted)
{
    __shared__ int s[NP];
    __shared__ int cur[NP];
    int b = blockIdx.x, t = threadIdx.x;
    cur[t] = 0;
    __syncthreads();
    int pv[NR / 1024];
    #pragma unroll
    for (int k = 0; k < NR / 1024; ++k) {
        pv[k] = recv[b * NR + k * 1024 + t] & 1023;
        atomicAdd(&cur[pv[k]], 1);
    }
    __syncthreads();
    int v = cur[t];
    s[t] = v;
    __syncthreads();
    #pragma unroll
    for (int off = 1; off < NP; off <<= 1) {
        int add = (t >= off) ? s[t - off] : 0;
        __syncthreads();
        s[t] += add;
        __syncthreads();
    }
    int excl = s[t] - v;                              // exclusive prefix
    row_ptr[b * (NP + 1) + t] = excl;
    cur[t] = excl;
    if (t == NP - 1) row_ptr[b * (NP + 1) + NP] = s[t];
    __syncthreads();
    #pragma unroll
    for (int k = 0; k < NR / 1024; ++k) {
        int r = k * 1024 + t;
        int j = atomicAdd(&cur[pv[k]], 1) & 8191;
        pos[b * NR + r] = (u16)j;
        send_sorted[b * NR + j] = send[b * NR + r];
    }
}

// ---------------- MFMA tile core (MT*16 rows x 128 cols per block) ----------------
template<int KC>
static __device__ __forceinline__ void load_wfrag(
    const bf16x8* __restrict__ fb, bf16x8 (&wf)[KC][2], int tid)
{
    #pragma unroll
    for (int kc = 0; kc < KC; ++kc)
      #pragma unroll
      for (int nt = 0; nt < 2; ++nt)
        wf[kc][nt] = fb[(kc*2 + nt)*256 + tid];
}

template<int MT, int KC, int LDA>
static __device__ __forceinline__ void mfma_compute(
    const u16* xlds, const bf16x8 (&wf)[KC][2], f32x4 (&acc)[MT][2],
    int l16, int quad)
{
    #pragma unroll
    for (int kc = 0; kc < KC; ++kc) {
        bf16x8 a[MT];
        #pragma unroll
        for (int mt = 0; mt < MT; ++mt)
            a[mt] = *(const bf16x8*)(xlds + (mt*16 + l16)*LDA + kc*32 + quad*8);
        #pragma unroll
        for (int mt = 0; mt < MT; ++mt) {
            acc[mt][0] = MFMA(a[mt], wf[kc][0], acc[mt][0], 0, 0, 0);
            acc[mt][1] = MFMA(a[mt], wf[kc][1], acc[mt][1], 0, 0, 0);
        }
    }
}

template<int MT>
static __device__ __forceinline__ void zero_acc(f32x4 (&acc)[MT][2]) {
    #pragma unroll
    for (int mt = 0; mt < MT; ++mt)
      #pragma unroll
      for (int nt = 0; nt < 2; ++nt)
        acc[mt][nt] = f32x4{0.f, 0.f, 0.f, 0.f};
}

template<int MT, int LDA>
static __device__ __forceinline__ void store_c_lds(
    u16* xlds, const f32x4 (&acc)[MT][2], const float* __restrict__ bias,
    int wave, int quad, int l16, int coloff = 0)
{
    #pragma unroll
    for (int mt = 0; mt < MT; ++mt)
      #pragma unroll
      for (int nt = 0; nt < 2; ++nt) {
        int col = wave*32 + nt*16 + l16;
        float bv = bias[col];
        #pragma unroll
        for (int rg = 0; rg < 4; ++rg)
            xlds[(mt*16 + quad*4 + rg)*LDA + coloff + col] =
                (u16)f2bf(fmaxf(acc[mt][nt][rg] + bv, 0.f));
      }
}

template<int MT, bool RELU>
static __device__ __forceinline__ void store_c_glob(
    u16* __restrict__ out, long row0, const f32x4 (&acc)[MT][2],
    const float* __restrict__ bias, int wave, int quad, int l16)
{
    #pragma unroll
    for (int mt = 0; mt < MT; ++mt)
      #pragma unroll
      for (int nt = 0; nt < 2; ++nt) {
        int col = wave*32 + nt*16 + l16;
        float bv = bias[col];
        #pragma unroll
        for (int rg = 0; rg < 4; ++rg) {
            long r = row0 + mt*16 + quad*4 + rg;
            float v = acc[mt][nt][rg] + bv;
            if (RELU) v = fmaxf(v, 0.f);
            out[r*128 + col] = (u16)f2bf(v);
        }
      }
}

// ------- fused encoders: blocks [0,1024) relation (3 layers + P, CSR-scattered);
//         [1024,1152) particle (2 layers) -------
__global__ __launch_bounds__(256) void k_encpe(
    const float* __restrict__ state, const float* __restrict__ Ra,
    const u16* __restrict__ recv, const u16* __restrict__ send,
    const u16* __restrict__ pos,
    const bf16x8* __restrict__ f_re0, const float* __restrict__ re_b0,
    const bf16x8* __restrict__ f_re1, const float* __restrict__ re_b1,
    const bf16x8* __restrict__ f_re2, const float* __restrict__ re_b2,
    const bf16x8* __restrict__ f_rpP, const float* __restrict__ rp_b,
    u16* __restrict__ bufP,
    const bf16x8* __restrict__ f_pe0, const float* __restrict__ pe_b0,
    const bf16x8* __restrict__ f_pe1, const float* __restrict__ pe_b1,
    u16* __restrict__ penc)
{
    constexpr int LDA = 136;                   // 128 + 8 (also holds 96-col input)
    __shared__ __align__(16) u16 xlds[64 * LDA];
    const int tid = threadIdx.x;
    const int wave = tid >> 6, quad = (tid >> 4) & 3, l16 = tid & 15;
    f32x4 acc[4][2];

    if (blockIdx.x < 1024) {                   // ---- relation path ----
        const int row0 = blockIdx.x * 64;
        const int b = row0 >> 13;
        {   // stage gathered input: [state_recv(32) | state_send(32) | Ra(1) | zeros->96]
            int r = tid >> 2, tt = tid & 3;
            int rel = row0 + r;
            u16* dst = xlds + r * LDA;
            int ri = recv[rel] & 1023;
            int si = send[rel] & 1023;
            const float* rrow = state + ((long)(b*NP + ri)) * 32;
            const float* srow = state + ((long)(b*NP + si)) * 32;
            float4 a0 = *(const float4*)(rrow + tt*8);
            float4 a1 = *(const float4*)(rrow + tt*8 + 4);
            uint4 o;
            o.x = pack2(a0.x, a0.y); o.y = pack2(a0.z, a0.w);
            o.z = pack2(a1.x, a1.y); o.w = pack2(a1.z, a1.w);
            *(uint4*)(dst + tt*8) = o;
            float4 s0 = *(const float4*)(srow + tt*8);
            float4 s1 = *(const float4*)(srow + tt*8 + 4);
            o.x = pack2(s0.x, s0.y); o.y = pack2(s0.z, s0.w);
            o.z = pack2(s1.x, s1.y); o.w = pack2(s1.z, s1.w);
            *(uint4*)(dst + 32 + tt*8) = o;
            if (tt == 3) {
                uint4 z = make_uint4(0, 0, 0, 0);
                *(uint4*)(dst + 64) = z; *(uint4*)(dst + 72) = z;
                *(uint4*)(dst + 80) = z; *(uint4*)(dst + 88) = z;
                dst[64] = (u16)f2bf(Ra[rel]);
            }
        }
        __syncthreads();
        zero_acc<4>(acc);
        {
            bf16x8 wf[3][2];
            load_wfrag<3>(f_re0, wf, tid);
            mfma_compute<4, 3, LDA>(xlds, wf, acc, l16, quad);
        }
        __syncthreads();
        store_c_lds<4, LDA>(xlds, acc, re_b0, wave, quad, l16);
        __syncthreads();
        zero_acc<4>(acc);
        {
            bf16x8 wf[4][2];
            load_wfrag<4>(f_re1, wf, tid);
            mfma_compute<4, 4, LDA>(xlds, wf, acc, l16, quad);
        }
        __syncthreads();
        store_c_lds<4, LDA>(xlds, acc, re_b1, wave, quad, l16);
        __syncthreads();
        zero_acc<4>(acc);
        {
            bf16x8 wf[4][2];
            load_wfrag<4>(f_re2, wf, tid);
            mfma_compute<4, 4, LDA>(xlds, wf, acc, l16, quad);
        }
        __syncthreads();
        store_c_lds<4, LDA>(xlds, acc, re_b2, wave, quad, l16);   // relation_encode
        __syncthreads();
        zero_acc<4>(acc);
        {
            bf16x8 wf[4][2];
            load_wfrag<4>(f_rpP, wf, tid);
            mfma_compute<4, 4, LDA>(xlds, wf, acc, l16, quad);
        }
        // P (pre-relu) scattered to CSR-sorted position: bufP[b*NR + pos[rel]]
        #pragma unroll
        for (int mt = 0; mt < 4; ++mt)
          #pragma unroll
          for (int nt = 0; nt < 2; ++nt) {
            int col = wave*32 + nt*16 + l16;
            float bv = rp_b[col];
            #pragma unroll
            for (int rg = 0; rg < 4; ++rg) {
                int rl = mt*16 + quad*4 + rg;
                int j = pos[row0 + rl] & 8191;
                bufP[((long)(b*NR + j))*128 + col] = (u16)f2bf(acc[mt][nt][rg] + bv);
            }
          }
    } else {                                   // ---- particle path ----
        const long row0 = (long)(blockIdx.x - 1024) * 64;
        for (int idx = tid; idx < 64 * 8; idx += 256) {    // stage state fp32->bf16
            int r = idx >> 3, c = idx & 7;
            float4 v = *(const float4*)(state + (row0 + r)*32 + c*4);
            uint2 o; o.x = pack2(v.x, v.y); o.y = pack2(v.z, v.w);
            *(uint2*)(xlds + r*LDA + c*4) = o;
        }
        __syncthreads();
        zero_acc<4>(acc);
        {
            bf16x8 wf[1][2];
            load_wfrag<1>(f_pe0, wf, tid);
            mfma_compute<4, 1, LDA>(xlds, wf, acc, l16, quad);
        }
        __syncthreads();
        store_c_lds<4, LDA>(xlds, acc, pe_b0, wave, quad, l16);
        __syncthreads();
        zero_acc<4>(acc);
        {
            bf16x8 wf[4][2];
            load_wfrag<4>(f_pe1, wf, tid);
            mfma_compute<4, 4, LDA>(xlds, wf, acc, l16, quad);
        }
        store_c_glob<4, true>(penc, row0, acc, pe_b1, wave, quad, l16);
    }
}

// ------- particle propagator (32 rows/block, 256 blocks):
//   agg = sum over CSR range [s0,e0) of relu(P_sorted[j] + U[p] + V[send_sorted[j]]);
//   peff = relu([penc|agg]@pp_w + b + prev);
//   epilogue: UV for next step (MAKEUV) or fused predictor (LAST) -------
template<bool STEP1, bool MAKEUV, bool LAST>
__global__ __launch_bounds__(256) void k_pp(
    const u16* __restrict__ penc, const u16* __restrict__ bufP,
    const u16* __restrict__ UV_in, u16* __restrict__ UV_out,
    const int* __restrict__ row_ptr, const u16* __restrict__ send_sorted,
    const bf16x8* __restrict__ f_pp, const float* __restrict__ pp_b,
    const bf16x8* __restrict__ f_U, const bf16x8* __restrict__ f_V,
    const bf16x8* __restrict__ f_pr0, const float* __restrict__ pr_b0,
    const float* __restrict__ pr_w1, const float* __restrict__ pr_b1,
    float* __restrict__ peff32_io, float* __restrict__ out)
{
    constexpr int LDA = 264;                   // 256 + 8
    __shared__ __align__(16) u16 xlds[32 * LDA];
    const int tid = threadIdx.x;
    const int wave = tid >> 6, quad = (tid >> 4) & 3, l16 = tid & 15;
    const long row0 = (long)blockIdx.x * 32;

    for (int idx = tid; idx < 512; idx += 256) {           // seg0: particle_encode (bf16)
        int r = idx >> 4, c = idx & 15;
        *(uint4*)(xlds + r*LDA + c*8) = *(const uint4*)(penc + (row0 + r)*128 + c*8);
    }
    {   // seg1: agg; 8 threads/particle, 16 cols each; bufP streamed
        int pp = tid >> 3;
        int cq = tid & 7;
        int gp = (int)row0 + pp;
        int b = gp >> 10, pl = gp & 1023;
        const int* rp = row_ptr + b * (NP + 1);
        int s0 = rp[pl], e0 = rp[pl + 1];
        float a[16];
        #pragma unroll
        for (int t = 0; t < 16; ++t) a[t] = 0.f;
        float uv[16];
        if (!STEP1) {
            const u16* ur = UV_in + ((long)gp)*256 + cq*16;
            unpk8(*(const uint4*)ur, uv);
            unpk8(*(const uint4*)(ur + 8), uv + 8);
        }
        for (int j = s0; j < e0; ++j) {
            const u16* prow = bufP + ((long)(b*NR + j))*128 + cq*16;
            float pv[16];
            unpk8(*(const uint4*)prow, pv);
            unpk8(*(const uint4*)(prow + 8), pv + 8);
            if (STEP1) {
                #pragma unroll
                for (int e = 0; e < 16; ++e) a[e] += fmaxf(pv[e], 0.f);
            } else {
                int sj = send_sorted[b * NR + j] & 1023;
                const u16* vrow = UV_in + ((long)(b*NP + sj))*256 + 128 + cq*16;
                float vv[16];
                unpk8(*(const uint4*)vrow, vv);
                unpk8(*(const uint4*)(vrow + 8), vv + 8);
                #pragma unroll
                for (int e = 0; e < 16; ++e)
                    a[e] += fmaxf(pv[e] + uv[e] + vv[e], 0.f);
            }
        }
        u16* dst = xlds + pp*LDA + 128 + cq*16;
        uint4 o;
        o.x = pack2(a[0], a[1]);   o.y = pack2(a[2], a[3]);
        o.z = pack2(a[4], a[5]);   o.w = pack2(a[6], a[7]);
        *(uint4*)dst = o;
        o.x = pack2(a[8], a[9]);   o.y = pack2(a[10], a[11]);
        o.z = pack2(a[12], a[13]); o.w = pack2(a[14], a[15]);
        *(uint4*)(dst + 8) = o;
    }
    __syncthreads();

    f32x4 acc[2][2];
    {
        bf16x8 wf[8][2];
        load_wfrag<8>(f_pp, wf, tid);
        zero_acc<2>(acc);
        mfma_compute<2, 8, LDA>(xlds, wf, acc, l16, quad);
    }
    __syncthreads();                                       // A-reads done before overwrite

    // epilogue 1: peff = relu(acc + b + prev); write global (unless LAST) + LDS cols[0,128)
    #pragma unroll
    for (int mt = 0; mt < 2; ++mt)
      #pragma unroll
      for (int nt = 0; nt < 2; ++nt) {
        int col = wave*32 + nt*16 + l16;
        float bv = pp_b[col];
        #pragma unroll
        for (int rg = 0; rg < 4; ++rg) {
            int rloc = mt*16 + quad*4 + rg;
            long r = row0 + rloc;
            float prev = STEP1 ? 0.f : peff32_io[r*128 + col];
            float v = fmaxf(acc[mt][nt][rg] + bv + prev, 0.f);
            if (!LAST) peff32_io[r*128 + col] = v;
            xlds[rloc*LDA + col] = (u16)f2bf(v);
        }
      }
    __syncthreads();

    if (MAKEUV) {   // epilogue 2a: UV_out = peff @ [rp_w1 | rp_w2]
        #pragma unroll
        for (int half = 0; half < 2; ++half) {
            bf16x8 wf[4][2];
            load_wfrag<4>(half ? f_V : f_U, wf, tid);
            zero_acc<2>(acc);
            mfma_compute<2, 4, LDA>(xlds, wf, acc, l16, quad);
            #pragma unroll
            for (int mt = 0; mt < 2; ++mt)
              #pragma unroll
              for (int nt = 0; nt < 2; ++nt) {
                int col = half*128 + wave*32 + nt*16 + l16;
                #pragma unroll
                for (int rg = 0; rg < 4; ++rg) {
                    long r = row0 + mt*16 + quad*4 + rg;
                    UV_out[r*256 + col] = (u16)f2bf(acc[mt][nt][rg]);
                }
              }
        }
    }
    if (LAST) {     // epilogue 2b: fused predictor
        bf16x8 wf[4][2];
        load_wfrag<4>(f_pr0, wf, tid);
        zero_acc<2>(acc);
        mfma_compute<2, 4, LDA>(xlds, wf, acc, l16, quad);
        store_c_lds<2, LDA>(xlds, acc, pr_b0, wave, quad, l16, 128);  // h -> cols [128,256)
        __syncthreads();
        if (tid < 96) {                                    // 32 rows x 3 cols
            int row = tid / 3, col = tid - row * 3;
            float s = pr_b1[col];
            const u16* hr = xlds + row * LDA + 128;
            #pragma unroll 8
            for (int k = 0; k < 128; ++k) s += bf2f(hr[k]) * pr_w1[k*3 + col];
            out[(row0 + row)*3 + col] = s;
        }
    }
}

extern "C" void kernel_launch(void* const* d_in, const int* in_sizes, int n_in,
                              void* d_out, int out_size, void* d_ws, size_t ws_size,
                              hipStream_t stream) {
    const float* state = (const float*)d_in[0];
    const float* Rr    = (const float*)d_in[1];
    const float* Rs    = (const float*)d_in[2];
    const float* Ra    = (const float*)d_in[3];
    // d_in[4] = pstep (=3, constant)
    const float* pe_w0 = (const float*)d_in[5];
    const float* pe_b0 = (const float*)d_in[6];
    const float* pe_w1 = (const float*)d_in[7];
    const float* pe_b1 = (const float*)d_in[8];
    const float* re_w0 = (const float*)d_in[9];
    const float* re_b0 = (const float*)d_in[10];
    const float* re_w1 = (const float*)d_in[11];
    const float* re_b1 = (const float*)d_in[12];
    const float* re_w2 = (const float*)d_in[13];
    const float* re_b2 = (const float*)d_in[14];
    const float* rp_w  = (const float*)d_in[15];
    const float* rp_b  = (const float*)d_in[16];
    const float* pp_w  = (const float*)d_in[17];
    const float* pp_b  = (const float*)d_in[18];
    const float* pr_w0 = (const float*)d_in[19];
    const float* pr_b0 = (const float*)d_in[20];
    const float* pr_w1 = (const float*)d_in[21];
    const float* pr_b1 = (const float*)d_in[22];

    // workspace layout (ws_size = 1 GB; peak use ~31 MB)
    char* p = (char*)d_ws;
    u16*    bufP    = (u16*)p;    p += (size_t)NB*NR*128*2;      // 16 MB  P (CSR-sorted)
    u16*    UVa     = (u16*)p;    p += (size_t)NB*NP*256*2;      // 4 MB
    u16*    UVb     = (u16*)p;    p += (size_t)NB*NP*256*2;      // 4 MB
    float*  peff32  = (float*)p;  p += (size_t)NB*NP*128*4;      // 4 MB
    u16*    penc    = (u16*)p;    p += (size_t)NB*NP*128*2;      // 2 MB
    bf16x8* wfrag   = (bf16x8*)p; p += (size_t)80*256*16;        // 320 KB
    int*    row_ptr = (int*)p;    p += (size_t)NB*(NP+1)*4 + 12; // ~32 KB (+pad)
    u16*    recv    = (u16*)p;    p += (size_t)NB*NR*2;          // 128 KB
    u16*    send    = (u16*)p;    p += (size_t)NB*NR*2;          // 128 KB
    u16*    pos     = (u16*)p;    p += (size_t)NB*NR*2;          // 128 KB
    u16*    send_s  = (u16*)p;    p += (size_t)NB*NR*2;          // 128 KB

    // frag-slot offsets
    const bf16x8* f_re0 = wfrag + 0*256;
    const bf16x8* f_re1 = wfrag + 6*256;
    const bf16x8* f_re2 = wfrag + 14*256;
    const bf16x8* f_pe0 = wfrag + 22*256;
    const bf16x8* f_pe1 = wfrag + 24*256;
    const bf16x8* f_rpP = wfrag + 32*256;   // rp_w rows [0,128)
    const bf16x8* f_rpU = wfrag + 40*256;   // rp_w rows [128,256)
    const bf16x8* f_rpV = wfrag + 48*256;   // rp_w rows [256,384)
    const bf16x8* f_pp  = wfrag + 56*256;
    const bf16x8* f_pr0 = wfrag + 72*256;

    float* outp = (float*)d_out;

    // 0) fused weight prep + one-hot index scan (4 chunks/thread); then CSR
    k_idxprep<<<16392, 256, 0, stream>>>((const uint4*)Rr, (const uint4*)Rs, recv, send,
                                         re_w0, re_w1, re_w2, pe_w0, pe_w1, rp_w, pp_w, pr_w0,
                                         wfrag);
    k_csr<<<NB, 1024, 0, stream>>>(recv, send, row_ptr, pos, send_s);
    // 1) fused encoders (relation 3 layers + P scattered to CSR order | particle 2 layers)
    k_encpe<<<1152, 256, 0, stream>>>(state, Ra, recv, send, pos,
                                      f_re0, re_b0, f_re1, re_b1, f_re2, re_b2,
                                      f_rpP, rp_b, bufP,
                                      f_pe0, pe_b0, f_pe1, pe_b1, penc);
    // 2) propagation: step 1 (U=V=0, makes UVa), step 2 (UVa -> UVb), step 3 (UVb -> pred)
    k_pp<true,  true,  false><<<256, 256, 0, stream>>>(
        penc, bufP, UVa, UVa, row_ptr, send_s, f_pp, pp_b,
        f_rpU, f_rpV, f_pr0, pr_b0, pr_w1, pr_b1, peff32, outp);
    k_pp<false, true,  false><<<256, 256, 0, stream>>>(
        penc, bufP, UVa, UVb, row_ptr, send_s, f_pp, pp_b,
        f_rpU, f_rpV, f_pr0, pr_b0, pr_w1, pr_b1, peff32, outp);
    k_pp<false, false, true><<<256, 256, 0, stream>>>(
        penc, bufP, UVb, UVa, row_ptr, send_s, f_pp, pp_b,
        f_rpU, f_rpV, f_pr0, pr_b0, pr_w1, pr_b1, peff32, outp);
}

// Round 10
// 620.820 us; speedup vs baseline: 1.0646x; 1.0646x over previous
//
#include <hip/hip_runtime.h>

#define NB 8
#define NP 1024
#define NR 8192

typedef unsigned short u16;
typedef __attribute__((ext_vector_type(8))) short bf16x8;   // 8 bf16 (4 VGPRs)
typedef __attribute__((ext_vector_type(4))) float f32x4;
typedef __attribute__((ext_vector_type(4))) unsigned int u32x4;

#define MFMA __builtin_amdgcn_mfma_f32_16x16x32_bf16

static __device__ __forceinline__ float bf2f(u16 u) {
    union { unsigned int i; float f; } v; v.i = ((unsigned int)u) << 16; return v.f;
}
static __device__ __forceinline__ unsigned int f2bf(float f) {
    union { float fv; unsigned int i; } v; v.fv = f;
    unsigned int r = v.i + 0x7FFFu + ((v.i >> 16) & 1u);   // RNE
    return r >> 16;
}
static __device__ __forceinline__ unsigned int pack2(float a, float b) {
    return f2bf(a) | (f2bf(b) << 16);
}
static __device__ __forceinline__ void unpk8(uint4 v, float* o) {
    o[0] = bf2f((u16)(v.x & 0xFFFF)); o[1] = bf2f((u16)(v.x >> 16));
    o[2] = bf2f((u16)(v.y & 0xFFFF)); o[3] = bf2f((u16)(v.y >> 16));
    o[4] = bf2f((u16)(v.z & 0xFFFF)); o[5] = bf2f((u16)(v.z >> 16));
    o[6] = bf2f((u16)(v.w & 0xFFFF)); o[7] = bf2f((u16)(v.w >> 16));
}

// ------- fused: blocks 0..7 = weight prep; blocks 8.. = one-hot index scan -------
// Scan: each block reads ONE matrix (parity-interleaved), 2 chunks/thread,
// non-temporal loads (no L3 allocation -> no thrash of the restore-resident half).
__global__ __launch_bounds__(256) void k_idxprep(
    const u32x4* __restrict__ Rr4, const u32x4* __restrict__ Rs4,
    u16* __restrict__ recv, u16* __restrict__ send,
    const float* __restrict__ w0, const float* __restrict__ w1,
    const float* __restrict__ w2, const float* __restrict__ w3,
    const float* __restrict__ w4, const float* __restrict__ w5,
    const float* __restrict__ w6, const float* __restrict__ w7,
    bf16x8* __restrict__ wfrag)
{
    int tid = threadIdx.x;
    if (blockIdx.x < 8) {                     // ---- weight prep path ----
        const float* W; int KC, kv, off;
        switch (blockIdx.x) {
            case 0:  W = w0; KC = 3;  kv = 65;  off = 0;  break;   // re_w0 (pad 65->96)
            case 1:  W = w1; KC = 4;  kv = 128; off = 6;  break;   // re_w1
            case 2:  W = w2; KC = 4;  kv = 128; off = 14; break;   // re_w2
            case 3:  W = w3; KC = 1;  kv = 32;  off = 22; break;   // pe_w0
            case 4:  W = w4; KC = 4;  kv = 128; off = 24; break;   // pe_w1
            case 5:  W = w5; KC = 12; kv = 384; off = 32; break;   // rp_w
            case 6:  W = w6; KC = 8;  kv = 256; off = 56; break;   // pp_w
            default: W = w7; KC = 4;  kv = 128; off = 72; break;   // pr_w0
        }
        int wave = tid >> 6, quad = (tid >> 4) & 3, l16 = tid & 15;
        for (int kc = 0; kc < KC; ++kc)
          for (int nt = 0; nt < 2; ++nt) {
            bf16x8 f;
            #pragma unroll
            for (int j = 0; j < 8; ++j) {
                int k = kc*32 + quad*8 + j;
                f[j] = (k < kv) ? (short)f2bf(W[k*128 + wave*32 + nt*16 + l16]) : (short)0;
            }
            wfrag[(off + kc*2 + nt)*256 + tid] = f;
          }
        return;
    }
    // ---- index scan path: single-matrix block, 2 chunks/thread, NT loads ----
    int sid = blockIdx.x - 8;
    int mat = sid & 1;
    const u32x4* src = mat ? Rs4 : Rr4;
    u16* dst = mat ? send : recv;
    long base = (long)(sid >> 1) * 512;
    long i0 = base + tid;
    long i1 = base + 256 + tid;
    u32x4 v0 = __builtin_nontemporal_load(src + i0);
    u32x4 v1 = __builtin_nontemporal_load(src + i1);
    {
        int c4 = (int)(i0 & 2047), n = (int)((i0 >> 11) & 1023), b = (int)(i0 >> 21);
        int o = b * NR + c4 * 4;
        if (v0[0]) dst[o + 0] = (u16)n;
        if (v0[1]) dst[o + 1] = (u16)n;
        if (v0[2]) dst[o + 2] = (u16)n;
        if (v0[3]) dst[o + 3] = (u16)n;
    }
    {
        int c4 = (int)(i1 & 2047), n = (int)((i1 >> 11) & 1023), b = (int)(i1 >> 21);
        int o = b * NR + c4 * 4;
        if (v1[0]) dst[o + 0] = (u16)n;
        if (v1[1]) dst[o + 1] = (u16)n;
        if (v1[2]) dst[o + 2] = (u16)n;
        if (v1[3]) dst[o + 3] = (u16)n;
    }
}

// ------- CSR: LDS histogram + scan; emits row_ptr, inverse perm pos[], send_sorted[] -------
__global__ __launch_bounds__(1024) void k_csr(
    const u16* __restrict__ recv, const u16* __restrict__ send,
    int* __restrict__ row_ptr, u16* __restrict__ pos,
    u16* __restrict__ send_sorted)
{
    __shared__ int s[NP];
    __shared__ int cur[NP];
    int b = blockIdx.x, t = threadIdx.x;
    cur[t] = 0;
    __syncthreads();
    int pv[NR / 1024];
    #pragma unroll
    for (int k = 0; k < NR / 1024; ++k) {
        pv[k] = recv[b * NR + k * 1024 + t] & 1023;
        atomicAdd(&cur[pv[k]], 1);
    }
    __syncthreads();
    int v = cur[t];
    s[t] = v;
    __syncthreads();
    #pragma unroll
    for (int off = 1; off < NP; off <<= 1) {
        int add = (t >= off) ? s[t - off] : 0;
        __syncthreads();
        s[t] += add;
        __syncthreads();
    }
    int excl = s[t] - v;                              // exclusive prefix
    row_ptr[b * (NP + 1) + t] = excl;
    cur[t] = excl;
    if (t == NP - 1) row_ptr[b * (NP + 1) + NP] = s[t];
    __syncthreads();
    #pragma unroll
    for (int k = 0; k < NR / 1024; ++k) {
        int r = k * 1024 + t;
        int j = atomicAdd(&cur[pv[k]], 1) & 8191;
        pos[b * NR + r] = (u16)j;
        send_sorted[b * NR + j] = send[b * NR + r];
    }
}

// ---------------- MFMA tile core (MT*16 rows x 128 cols per block) ----------------
template<int KC>
static __device__ __forceinline__ void load_wfrag(
    const bf16x8* __restrict__ fb, bf16x8 (&wf)[KC][2], int tid)
{
    #pragma unroll
    for (int kc = 0; kc < KC; ++kc)
      #pragma unroll
      for (int nt = 0; nt < 2; ++nt)
        wf[kc][nt] = fb[(kc*2 + nt)*256 + tid];
}

template<int MT, int KC, int LDA>
static __device__ __forceinline__ void mfma_compute(
    const u16* xlds, const bf16x8 (&wf)[KC][2], f32x4 (&acc)[MT][2],
    int l16, int quad)
{
    #pragma unroll
    for (int kc = 0; kc < KC; ++kc) {
        bf16x8 a[MT];
        #pragma unroll
        for (int mt = 0; mt < MT; ++mt)
            a[mt] = *(const bf16x8*)(xlds + (mt*16 + l16)*LDA + kc*32 + quad*8);
        #pragma unroll
        for (int mt = 0; mt < MT; ++mt) {
            acc[mt][0] = MFMA(a[mt], wf[kc][0], acc[mt][0], 0, 0, 0);
            acc[mt][1] = MFMA(a[mt], wf[kc][1], acc[mt][1], 0, 0, 0);
        }
    }
}

template<int MT>
static __device__ __forceinline__ void zero_acc(f32x4 (&acc)[MT][2]) {
    #pragma unroll
    for (int mt = 0; mt < MT; ++mt)
      #pragma unroll
      for (int nt = 0; nt < 2; ++nt)
        acc[mt][nt] = f32x4{0.f, 0.f, 0.f, 0.f};
}

template<int MT, int LDA>
static __device__ __forceinline__ void store_c_lds(
    u16* xlds, const f32x4 (&acc)[MT][2], const float* __restrict__ bias,
    int wave, int quad, int l16, int coloff = 0)
{
    #pragma unroll
    for (int mt = 0; mt < MT; ++mt)
      #pragma unroll
      for (int nt = 0; nt < 2; ++nt) {
        int col = wave*32 + nt*16 + l16;
        float bv = bias[col];
        #pragma unroll
        for (int rg = 0; rg < 4; ++rg)
            xlds[(mt*16 + quad*4 + rg)*LDA + coloff + col] =
                (u16)f2bf(fmaxf(acc[mt][nt][rg] + bv, 0.f));
      }
}

template<int MT, bool RELU>
static __device__ __forceinline__ void store_c_glob(
    u16* __restrict__ out, long row0, const f32x4 (&acc)[MT][2],
    const float* __restrict__ bias, int wave, int quad, int l16)
{
    #pragma unroll
    for (int mt = 0; mt < MT; ++mt)
      #pragma unroll
      for (int nt = 0; nt < 2; ++nt) {
        int col = wave*32 + nt*16 + l16;
        float bv = bias[col];
        #pragma unroll
        for (int rg = 0; rg < 4; ++rg) {
            long r = row0 + mt*16 + quad*4 + rg;
            float v = acc[mt][nt][rg] + bv;
            if (RELU) v = fmaxf(v, 0.f);
            out[r*128 + col] = (u16)f2bf(v);
        }
      }
}

// ------- fused encoders: blocks [0,1024) relation (3 layers + P, CSR-scattered);
//         [1024,1152) particle (2 layers) -------
__global__ __launch_bounds__(256) void k_encpe(
    const float* __restrict__ state, const float* __restrict__ Ra,
    const u16* __restrict__ recv, const u16* __restrict__ send,
    const u16* __restrict__ pos,
    const bf16x8* __restrict__ f_re0, const float* __restrict__ re_b0,
    const bf16x8* __restrict__ f_re1, const float* __restrict__ re_b1,
    const bf16x8* __restrict__ f_re2, const float* __restrict__ re_b2,
    const bf16x8* __restrict__ f_rpP, const float* __restrict__ rp_b,
    u16* __restrict__ bufP,
    const bf16x8* __restrict__ f_pe0, const float* __restrict__ pe_b0,
    const bf16x8* __restrict__ f_pe1, const float* __restrict__ pe_b1,
    u16* __restrict__ penc)
{
    constexpr int LDA = 136;                   // 128 + 8 (also holds 96-col input)
    __shared__ __align__(16) u16 xlds[64 * LDA];
    const int tid = threadIdx.x;
    const int wave = tid >> 6, quad = (tid >> 4) & 3, l16 = tid & 15;
    f32x4 acc[4][2];

    if (blockIdx.x < 1024) {                   // ---- relation path ----
        const int row0 = blockIdx.x * 64;
        const int b = row0 >> 13;
        {   // stage gathered input: [state_recv(32) | state_send(32) | Ra(1) | zeros->96]
            int r = tid >> 2, tt = tid & 3;
            int rel = row0 + r;
            u16* dst = xlds + r * LDA;
            int ri = recv[rel] & 1023;
            int si = send[rel] & 1023;
            const float* rrow = state + ((long)(b*NP + ri)) * 32;
            const float* srow = state + ((long)(b*NP + si)) * 32;
            float4 a0 = *(const float4*)(rrow + tt*8);
            float4 a1 = *(const float4*)(rrow + tt*8 + 4);
            uint4 o;
            o.x = pack2(a0.x, a0.y); o.y = pack2(a0.z, a0.w);
            o.z = pack2(a1.x, a1.y); o.w = pack2(a1.z, a1.w);
            *(uint4*)(dst + tt*8) = o;
            float4 s0 = *(const float4*)(srow + tt*8);
            float4 s1 = *(const float4*)(srow + tt*8 + 4);
            o.x = pack2(s0.x, s0.y); o.y = pack2(s0.z, s0.w);
            o.z = pack2(s1.x, s1.y); o.w = pack2(s1.z, s1.w);
            *(uint4*)(dst + 32 + tt*8) = o;
            if (tt == 3) {
                uint4 z = make_uint4(0, 0, 0, 0);
                *(uint4*)(dst + 64) = z; *(uint4*)(dst + 72) = z;
                *(uint4*)(dst + 80) = z; *(uint4*)(dst + 88) = z;
                dst[64] = (u16)f2bf(Ra[rel]);
            }
        }
        __syncthreads();
        zero_acc<4>(acc);
        {
            bf16x8 wf[3][2];
            load_wfrag<3>(f_re0, wf, tid);
            mfma_compute<4, 3, LDA>(xlds, wf, acc, l16, quad);
        }
        __syncthreads();
        store_c_lds<4, LDA>(xlds, acc, re_b0, wave, quad, l16);
        __syncthreads();
        zero_acc<4>(acc);
        {
            bf16x8 wf[4][2];
            load_wfrag<4>(f_re1, wf, tid);
            mfma_compute<4, 4, LDA>(xlds, wf, acc, l16, quad);
        }
        __syncthreads();
        store_c_lds<4, LDA>(xlds, acc, re_b1, wave, quad, l16);
        __syncthreads();
        zero_acc<4>(acc);
        {
            bf16x8 wf[4][2];
            load_wfrag<4>(f_re2, wf, tid);
            mfma_compute<4, 4, LDA>(xlds, wf, acc, l16, quad);
        }
        __syncthreads();
        store_c_lds<4, LDA>(xlds, acc, re_b2, wave, quad, l16);   // relation_encode
        __syncthreads();
        zero_acc<4>(acc);
        {
            bf16x8 wf[4][2];
            load_wfrag<4>(f_rpP, wf, tid);
            mfma_compute<4, 4, LDA>(xlds, wf, acc, l16, quad);
        }
        // P (pre-relu) scattered to CSR-sorted position: bufP[b*NR + pos[rel]]
        #pragma unroll
        for (int mt = 0; mt < 4; ++mt)
          #pragma unroll
          for (int nt = 0; nt < 2; ++nt) {
            int col = wave*32 + nt*16 + l16;
            float bv = rp_b[col];
            #pragma unroll
            for (int rg = 0; rg < 4; ++rg) {
                int rl = mt*16 + quad*4 + rg;
                int j = pos[row0 + rl] & 8191;
                bufP[((long)(b*NR + j))*128 + col] = (u16)f2bf(acc[mt][nt][rg] + bv);
            }
          }
    } else {                                   // ---- particle path ----
        const long row0 = (long)(blockIdx.x - 1024) * 64;
        for (int idx = tid; idx < 64 * 8; idx += 256) {    // stage state fp32->bf16
            int r = idx >> 3, c = idx & 7;
            float4 v = *(const float4*)(state + (row0 + r)*32 + c*4);
            uint2 o; o.x = pack2(v.x, v.y); o.y = pack2(v.z, v.w);
            *(uint2*)(xlds + r*LDA + c*4) = o;
        }
        __syncthreads();
        zero_acc<4>(acc);
        {
            bf16x8 wf[1][2];
            load_wfrag<1>(f_pe0, wf, tid);
            mfma_compute<4, 1, LDA>(xlds, wf, acc, l16, quad);
        }
        __syncthreads();
        store_c_lds<4, LDA>(xlds, acc, pe_b0, wave, quad, l16);
        __syncthreads();
        zero_acc<4>(acc);
        {
            bf16x8 wf[4][2];
            load_wfrag<4>(f_pe1, wf, tid);
            mfma_compute<4, 4, LDA>(xlds, wf, acc, l16, quad);
        }
        store_c_glob<4, true>(penc, row0, acc, pe_b1, wave, quad, l16);
    }
}

// ------- particle propagator (32 rows/block, 256 blocks):
//   agg = sum over CSR range [s0,e0) of relu(P_sorted[j] + U[p] + V[send_sorted[j]]);
//   peff = relu([penc|agg]@pp_w + b + prev);
//   epilogue: UV for next step (MAKEUV) or fused predictor (LAST) -------
template<bool STEP1, bool MAKEUV, bool LAST>
__global__ __launch_bounds__(256) void k_pp(
    const u16* __restrict__ penc, const u16* __restrict__ bufP,
    const u16* __restrict__ UV_in, u16* __restrict__ UV_out,
    const int* __restrict__ row_ptr, const u16* __restrict__ send_sorted,
    const bf16x8* __restrict__ f_pp, const float* __restrict__ pp_b,
    const bf16x8* __restrict__ f_U, const bf16x8* __restrict__ f_V,
    const bf16x8* __restrict__ f_pr0, const float* __restrict__ pr_b0,
    const float* __restrict__ pr_w1, const float* __restrict__ pr_b1,
    float* __restrict__ peff32_io, float* __restrict__ out)
{
    constexpr int LDA = 264;                   // 256 + 8
    __shared__ __align__(16) u16 xlds[32 * LDA];
    const int tid = threadIdx.x;
    const int wave = tid >> 6, quad = (tid >> 4) & 3, l16 = tid & 15;
    const long row0 = (long)blockIdx.x * 32;

    for (int idx = tid; idx < 512; idx += 256) {           // seg0: particle_encode (bf16)
        int r = idx >> 4, c = idx & 15;
        *(uint4*)(xlds + r*LDA + c*8) = *(const uint4*)(penc + (row0 + r)*128 + c*8);
    }
    {   // seg1: agg; 8 threads/particle, 16 cols each; bufP streamed
        int pp = tid >> 3;
        int cq = tid & 7;
        int gp = (int)row0 + pp;
        int b = gp >> 10, pl = gp & 1023;
        const int* rp = row_ptr + b * (NP + 1);
        int s0 = rp[pl], e0 = rp[pl + 1];
        float a[16];
        #pragma unroll
        for (int t = 0; t < 16; ++t) a[t] = 0.f;
        float uv[16];
        if (!STEP1) {
            const u16* ur = UV_in + ((long)gp)*256 + cq*16;
            unpk8(*(const uint4*)ur, uv);
            unpk8(*(const uint4*)(ur + 8), uv + 8);
        }
        for (int j = s0; j < e0; ++j) {
            const u16* prow = bufP + ((long)(b*NR + j))*128 + cq*16;
            float pv[16];
            unpk8(*(const uint4*)prow, pv);
            unpk8(*(const uint4*)(prow + 8), pv + 8);
            if (STEP1) {
                #pragma unroll
                for (int e = 0; e < 16; ++e) a[e] += fmaxf(pv[e], 0.f);
            } else {
                int sj = send_sorted[b * NR + j] & 1023;
                const u16* vrow = UV_in + ((long)(b*NP + sj))*256 + 128 + cq*16;
                float vv[16];
                unpk8(*(const uint4*)vrow, vv);
                unpk8(*(const uint4*)(vrow + 8), vv + 8);
                #pragma unroll
                for (int e = 0; e < 16; ++e)
                    a[e] += fmaxf(pv[e] + uv[e] + vv[e], 0.f);
            }
        }
        u16* dst = xlds + pp*LDA + 128 + cq*16;
        uint4 o;
        o.x = pack2(a[0], a[1]);   o.y = pack2(a[2], a[3]);
        o.z = pack2(a[4], a[5]);   o.w = pack2(a[6], a[7]);
        *(uint4*)dst = o;
        o.x = pack2(a[8], a[9]);   o.y = pack2(a[10], a[11]);
        o.z = pack2(a[12], a[13]); o.w = pack2(a[14], a[15]);
        *(uint4*)(dst + 8) = o;
    }
    __syncthreads();

    f32x4 acc[2][2];
    {
        bf16x8 wf[8][2];
        load_wfrag<8>(f_pp, wf, tid);
        zero_acc<2>(acc);
        mfma_compute<2, 8, LDA>(xlds, wf, acc, l16, quad);
    }
    __syncthreads();                                       // A-reads done before overwrite

    // epilogue 1: peff = relu(acc + b + prev); write global (unless LAST) + LDS cols[0,128)
    #pragma unroll
    for (int mt = 0; mt < 2; ++mt)
      #pragma unroll
      for (int nt = 0; nt < 2; ++nt) {
        int col = wave*32 + nt*16 + l16;
        float bv = pp_b[col];
        #pragma unroll
        for (int rg = 0; rg < 4; ++rg) {
            int rloc = mt*16 + quad*4 + rg;
            long r = row0 + rloc;
            float prev = STEP1 ? 0.f : peff32_io[r*128 + col];
            float v = fmaxf(acc[mt][nt][rg] + bv + prev, 0.f);
            if (!LAST) peff32_io[r*128 + col] = v;
            xlds[rloc*LDA + col] = (u16)f2bf(v);
        }
      }
    __syncthreads();

    if (MAKEUV) {   // epilogue 2a: UV_out = peff @ [rp_w1 | rp_w2]
        #pragma unroll
        for (int half = 0; half < 2; ++half) {
            bf16x8 wf[4][2];
            load_wfrag<4>(half ? f_V : f_U, wf, tid);
            zero_acc<2>(acc);
            mfma_compute<2, 4, LDA>(xlds, wf, acc, l16, quad);
            #pragma unroll
            for (int mt = 0; mt < 2; ++mt)
              #pragma unroll
              for (int nt = 0; nt < 2; ++nt) {
                int col = half*128 + wave*32 + nt*16 + l16;
                #pragma unroll
                for (int rg = 0; rg < 4; ++rg) {
                    long r = row0 + mt*16 + quad*4 + rg;
                    UV_out[r*256 + col] = (u16)f2bf(acc[mt][nt][rg]);
                }
              }
        }
    }
    if (LAST) {     // epilogue 2b: fused predictor
        bf16x8 wf[4][2];
        load_wfrag<4>(f_pr0, wf, tid);
        zero_acc<2>(acc);
        mfma_compute<2, 4, LDA>(xlds, wf, acc, l16, quad);
        store_c_lds<2, LDA>(xlds, acc, pr_b0, wave, quad, l16, 128);  // h -> cols [128,256)
        __syncthreads();
        if (tid < 96) {                                    // 32 rows x 3 cols
            int row = tid / 3, col = tid - row * 3;
            float s = pr_b1[col];
            const u16* hr = xlds + row * LDA + 128;
            #pragma unroll 8
            for (int k = 0; k < 128; ++k) s += bf2f(hr[k]) * pr_w1[k*3 + col];
            out[(row0 + row)*3 + col] = s;
        }
    }
}

extern "C" void kernel_launch(void* const* d_in, const int* in_sizes, int n_in,
                              void* d_out, int out_size, void* d_ws, size_t ws_size,
                              hipStream_t stream) {
    const float* state = (const float*)d_in[0];
    const float* Rr    = (const float*)d_in[1];
    const float* Rs    = (const float*)d_in[2];
    const float* Ra    = (const float*)d_in[3];
    // d_in[4] = pstep (=3, constant)
    const float* pe_w0 = (const float*)d_in[5];
    const float* pe_b0 = (const float*)d_in[6];
    const float* pe_w1 = (const float*)d_in[7];
    const float* pe_b1 = (const float*)d_in[8];
    const float* re_w0 = (const float*)d_in[9];
    const float* re_b0 = (const float*)d_in[10];
    const float* re_w1 = (const float*)d_in[11];
    const float* re_b1 = (const float*)d_in[12];
    const float* re_w2 = (const float*)d_in[13];
    const float* re_b2 = (const float*)d_in[14];
    const float* rp_w  = (const float*)d_in[15];
    const float* rp_b  = (const float*)d_in[16];
    const float* pp_w  = (const float*)d_in[17];
    const float* pp_b  = (const float*)d_in[18];
    const float* pr_w0 = (const float*)d_in[19];
    const float* pr_b0 = (const float*)d_in[20];
    const float* pr_w1 = (const float*)d_in[21];
    const float* pr_b1 = (const float*)d_in[22];

    // workspace layout (ws_size = 1 GB; peak use ~31 MB)
    char* p = (char*)d_ws;
    u16*    bufP    = (u16*)p;    p += (size_t)NB*NR*128*2;      // 16 MB  P (CSR-sorted)
    u16*    UVa     = (u16*)p;    p += (size_t)NB*NP*256*2;      // 4 MB
    u16*    UVb     = (u16*)p;    p += (size_t)NB*NP*256*2;      // 4 MB
    float*  peff32  = (float*)p;  p += (size_t)NB*NP*128*4;      // 4 MB
    u16*    penc    = (u16*)p;    p += (size_t)NB*NP*128*2;      // 2 MB
    bf16x8* wfrag   = (bf16x8*)p; p += (size_t)80*256*16;        // 320 KB
    int*    row_ptr = (int*)p;    p += (size_t)NB*(NP+1)*4 + 12; // ~32 KB (+pad)
    u16*    recv    = (u16*)p;    p += (size_t)NB*NR*2;          // 128 KB
    u16*    send    = (u16*)p;    p += (size_t)NB*NR*2;          // 128 KB
    u16*    pos     = (u16*)p;    p += (size_t)NB*NR*2;          // 128 KB
    u16*    send_s  = (u16*)p;    p += (size_t)NB*NR*2;          // 128 KB

    // frag-slot offsets
    const bf16x8* f_re0 = wfrag + 0*256;
    const bf16x8* f_re1 = wfrag + 6*256;
    const bf16x8* f_re2 = wfrag + 14*256;
    const bf16x8* f_pe0 = wfrag + 22*256;
    const bf16x8* f_pe1 = wfrag + 24*256;
    const bf16x8* f_rpP = wfrag + 32*256;   // rp_w rows [0,128)
    const bf16x8* f_rpU = wfrag + 40*256;   // rp_w rows [128,256)
    const bf16x8* f_rpV = wfrag + 48*256;   // rp_w rows [256,384)
    const bf16x8* f_pp  = wfrag + 56*256;
    const bf16x8* f_pr0 = wfrag + 72*256;

    float* outp = (float*)d_out;

    // 0) fused weight prep + one-hot index scan (NT loads, single-stream blocks); then CSR
    k_idxprep<<<65544, 256, 0, stream>>>((const u32x4*)Rr, (const u32x4*)Rs, recv, send,
                                         re_w0, re_w1, re_w2, pe_w0, pe_w1, rp_w, pp_w, pr_w0,
                                         wfrag);
    k_csr<<<NB, 1024, 0, stream>>>(recv, send, row_ptr, pos, send_s);
    // 1) fused encoders (relation 3 layers + P scattered to CSR order | particle 2 layers)
    k_encpe<<<1152, 256, 0, stream>>>(state, Ra, recv, send, pos,
                                      f_re0, re_b0, f_re1, re_b1, f_re2, re_b2,
                                      f_rpP, rp_b, bufP,
                                      f_pe0, pe_b0, f_pe1, pe_b1, penc);
    // 2) propagation: step 1 (U=V=0, makes UVa), step 2 (UVa -> UVb), step 3 (UVb -> pred)
    k_pp<true,  true,  false><<<256, 256, 0, stream>>>(
        penc, bufP, UVa, UVa, row_ptr, send_s, f_pp, pp_b,
        f_rpU, f_rpV, f_pr0, pr_b0, pr_w1, pr_b1, peff32, outp);
    k_pp<false, true,  false><<<256, 256, 0, stream>>>(
        penc, bufP, UVa, UVb, row_ptr, send_s, f_pp, pp_b,
        f_rpU, f_rpV, f_pr0, pr_b0, pr_w1, pr_b1, peff32, outp);
    k_pp<false, false, true><<<256, 256, 0, stream>>>(
        penc, bufP, UVb, UVa, row_ptr, send_s, f_pp, pp_b,
        f_rpU, f_rpV, f_pr0, pr_b0, pr_w1, pr_b1, peff32, outp);
}